// Round 1
// baseline (705.630 us; speedup 1.0000x reference)
//
#include <hip/hip_runtime.h>
#include <cstdint>
#include <cstddef>

typedef float f32x4 __attribute__((ext_vector_type(4)));
typedef __bf16 bf16x8 __attribute__((ext_vector_type(8)));
typedef unsigned short u16;

#define Hdim 128
#define DEdim 16
#define APITCH 296   // 592 B row: /16 aligned, 148 words %32 = 20 -> conflict-free b128
#define FPITCH 168   // 336 B row: /16 aligned, 84 words  %32 = 20 -> conflict-free b128
#define NPITCH 264   // 528 B row: /16 aligned, 132 words %32 = 4  -> 2-way (free)

__device__ __forceinline__ u16 f2bf(float f){
  uint32_t u = __builtin_bit_cast(uint32_t, f);
  u += 0x7fffu + ((u >> 16) & 1u);
  return (u16)(u >> 16);
}
__device__ __forceinline__ float silu_f(float x){
  return x / (1.0f + __expf(-x));
}

// One layer: C[64 rows][this wave's 32 cols] = A(LDS,bf16) @ Bt(global,bf16)^T + bias
// A-frag: A[rt*16 + (lane&15)][k],  k = kc*32 + (lane>>4)*8 + slot
// B-frag: B[k][ct*16 + (lane&15)]  (same k mapping -> mapping cancels)
// C/D (HW-verified): col = lane&15, row(reg i) = (lane>>4)*4 + i
template<int KC>
__device__ __forceinline__ void gemm_tile(
    const u16* A, int apitch,
    const u16* __restrict__ Bt, int kpad,
    const float* __restrict__ bias,
    int wv, int cidx, int hi, f32x4 (&acc)[4][2])
{
  const int c0 = (wv*2+0)*16 + cidx;
  const int c1 = (wv*2+1)*16 + cidx;
  const float b0 = bias[c0];
  const float b1 = bias[c1];
  #pragma unroll
  for (int rt=0; rt<4; ++rt){
    acc[rt][0] = (f32x4){b0,b0,b0,b0};
    acc[rt][1] = (f32x4){b1,b1,b1,b1};
  }
  #pragma unroll
  for (int kc=0; kc<KC; ++kc){
    const int ko = kc*32 + hi*8;
    bf16x8 bb0 = *(const bf16x8*)(Bt + (size_t)c0*kpad + ko);
    bf16x8 bb1 = *(const bf16x8*)(Bt + (size_t)c1*kpad + ko);
    #pragma unroll
    for (int rt=0; rt<4; ++rt){
      bf16x8 a = *(const bf16x8*)(A + (rt*16+cidx)*apitch + ko);
      acc[rt][0] = __builtin_amdgcn_mfma_f32_16x16x32_bf16(a, bb0, acc[rt][0], 0,0,0);
      acc[rt][1] = __builtin_amdgcn_mfma_f32_16x16x32_bf16(a, bb1, acc[rt][1], 0,0,0);
    }
  }
}

__global__ __launch_bounds__(256, 2) void egcl_edge(
    const float* __restrict__ h, const float* __restrict__ coord,
    const int* __restrict__ ei, const float* __restrict__ ea,
    const float* __restrict__ mes_b1, const float* __restrict__ mes_b2,
    const float* __restrict__ edge_b1, const float* __restrict__ edge_b2,
    const float* __restrict__ coord_b1, const float* __restrict__ coord_w2,
    const u16* __restrict__ w_mes1t, const u16* __restrict__ w_mes2t,
    const u16* __restrict__ w_coord1t, const u16* __restrict__ w_edge1t,
    const u16* __restrict__ w_edge2t,
    float* __restrict__ agg, float* __restrict__ out_coord,
    float* __restrict__ out_edge, int E, int N)
{
  __shared__ u16 Ab[64*APITCH];   // mes_in (288) -> later A2 / A6 in cols [0,128)
  __shared__ u16 Fb[64*FPITCH];   // edge_feat(128) | radial(1) | ea(16) | 0-pad(to 160)
  __shared__ float cds[64*4];     // coord_diff xyz, radial
  __shared__ float tvs[64];       // coord-MLP scalar per edge
  __shared__ int cnode[64];

  const int tid  = threadIdx.x;
  const int lane = tid & 63;
  const int wv   = tid >> 6;
  const int e0   = blockIdx.x * 64;
  const int cidx = lane & 15;
  const int hi   = lane >> 4;

  // ---------- stage: each wave stages its 16 edges ----------
  {
    const int le   = wv*16 + (lane>>2);
    const int part = lane & 3;
    int eg = e0 + le;
    if (eg >= E) eg = E-1;
    const int node = (part < 2) ? ei[eg] : ei[E + eg];   // parts 0,1: h[row]; 2,3: h[col]
    const float* src = h + (size_t)node*Hdim + (part&1)*64;
    u16* dst = Ab + le*APITCH + part*64;
    #pragma unroll
    for (int j=0;j<16;++j){
      const float4 v = ((const float4*)src)[j];
      ushort4 o; o.x=f2bf(v.x); o.y=f2bf(v.y); o.z=f2bf(v.z); o.w=f2bf(v.w);
      *(ushort4*)(dst + j*4) = o;
    }
    if (part == 0){
      const int cn = ei[E + eg];          // col node
      const float dx = coord[(size_t)node*3+0] - coord[(size_t)cn*3+0];
      const float dy = coord[(size_t)node*3+1] - coord[(size_t)cn*3+1];
      const float dz = coord[(size_t)node*3+2] - coord[(size_t)cn*3+2];
      const float radial = dx*dx + dy*dy + dz*dz;
      const float inv = 1.0f/(sqrtf(radial + 1e-8f) + 1.0f);
      cds[le*4+0]=dx*inv; cds[le*4+1]=dy*inv; cds[le*4+2]=dz*inv; cds[le*4+3]=radial;
      cnode[le] = cn;
      const u16 rb = f2bf(radial);
      Ab[le*APITCH + 256] = rb;
      Fb[le*FPITCH + 128] = rb;
      #pragma unroll
      for (int j=0;j<DEdim;++j){
        const u16 v = f2bf(ea[(size_t)eg*DEdim + j]);
        Ab[le*APITCH + 257 + j] = v;
        Fb[le*FPITCH + 129 + j] = v;
      }
      #pragma unroll
      for (int j=273;j<288;++j) Ab[le*APITCH + j] = 0;
      #pragma unroll
      for (int j=145;j<160;++j) Fb[le*FPITCH + j] = 0;
    }
    if (tid < 64) tvs[tid] = 0.f;
  }
  __syncthreads();                                   // B1

  f32x4 acc[4][2];

  // ---------- mes layer 1 (K=273 padded 288) ----------
  gemm_tile<9>(Ab, APITCH, w_mes1t, 288, mes_b1, wv, cidx, hi, acc);
  __syncthreads();                                   // B2: all reads of mes_in done
  #pragma unroll
  for (int rt=0; rt<4; ++rt)
    #pragma unroll
    for (int j=0;j<2;++j){
      const int col = (wv*2+j)*16 + cidx;
      #pragma unroll
      for (int i=0;i<4;++i)
        Ab[(rt*16 + hi*4 + i)*APITCH + col] = f2bf(silu_f(acc[rt][j][i]));
    }
  __syncthreads();                                   // B3

  // ---------- mes layer 2 -> edge_feat ----------
  gemm_tile<4>(Ab, APITCH, w_mes2t, 128, mes_b2, wv, cidx, hi, acc);
  #pragma unroll
  for (int rt=0; rt<4; ++rt)
    #pragma unroll
    for (int j=0;j<2;++j){
      const int col = (wv*2+j)*16 + cidx;
      #pragma unroll
      for (int i=0;i<4;++i){
        const int row = rt*16 + hi*4 + i;
        const float v = silu_f(acc[rt][j][i]);
        if (e0 + row < E)
          atomicAdd(agg + (size_t)cnode[row]*Hdim + col, v);   // segment_sum(edge_feat)
        Fb[row*FPITCH + col] = f2bf(v);
      }
    }
  __syncthreads();                                   // B4

  // ---------- coord layer 1 + GEMV with coord_w2 ----------
  gemm_tile<4>(Fb, FPITCH, w_coord1t, 128, coord_b1, wv, cidx, hi, acc);
  {
    const float cw0 = coord_w2[(wv*2+0)*16 + cidx];
    const float cw1 = coord_w2[(wv*2+1)*16 + cidx];
    #pragma unroll
    for (int rt=0; rt<4; ++rt)
      #pragma unroll
      for (int i=0;i<4;++i){
        float p = silu_f(acc[rt][0][i])*cw0 + silu_f(acc[rt][1][i])*cw1;
        p += __shfl_xor(p, 1);
        p += __shfl_xor(p, 2);
        p += __shfl_xor(p, 4);
        p += __shfl_xor(p, 8);
        if (cidx == 0) atomicAdd(&tvs[rt*16 + hi*4 + i], p);
      }
  }
  __syncthreads();                                   // B5
  if (tid < 192){
    const int le = tid/3, d = tid%3;
    if (e0 + le < E)
      atomicAdd(out_coord + (size_t)cnode[le]*3 + d, cds[le*4+d]*tvs[le]);
  }

  // ---------- edge layer 1 (K=145 padded 160) ----------
  gemm_tile<5>(Fb, FPITCH, w_edge1t, 160, edge_b1, wv, cidx, hi, acc);
  #pragma unroll
  for (int rt=0; rt<4; ++rt)
    #pragma unroll
    for (int j=0;j<2;++j){
      const int col = (wv*2+j)*16 + cidx;
      #pragma unroll
      for (int i=0;i<4;++i)
        Ab[(rt*16 + hi*4 + i)*APITCH + col] = f2bf(silu_f(acc[rt][j][i]));
    }
  __syncthreads();                                   // B6

  // ---------- edge layer 2 (no activation) ----------
  gemm_tile<4>(Ab, APITCH, w_edge2t, 128, edge_b2, wv, cidx, hi, acc);
  #pragma unroll
  for (int rt=0; rt<4; ++rt)
    #pragma unroll
    for (int j=0;j<2;++j){
      const int col = (wv*2+j)*16 + cidx;
      #pragma unroll
      for (int i=0;i<4;++i){
        const int row = rt*16 + hi*4 + i;
        const int eg = e0 + row;
        if (eg < E) out_edge[(size_t)eg*Hdim + col] = acc[rt][j][i];
      }
    }
}

__global__ __launch_bounds__(256, 2) void egcl_node(
    const float* __restrict__ h, const float* __restrict__ agg,
    const float* __restrict__ node_b1, const float* __restrict__ node_b2,
    const u16* __restrict__ w_node1t, const u16* __restrict__ w_node2t,
    float* __restrict__ out_h, int N)
{
  __shared__ u16 Ab[64*NPITCH];
  const int tid  = threadIdx.x;
  const int lane = tid & 63;
  const int wv   = tid >> 6;
  const int r0   = blockIdx.x * 64;
  const int cidx = lane & 15;
  const int hi   = lane >> 4;

  {
    const int le   = wv*16 + (lane>>2);
    const int part = lane & 3;
    int g = r0 + le;
    if (g >= N) g = N-1;
    const float* src = (part < 2) ? h   + (size_t)g*Hdim + part*64
                                  : agg + (size_t)g*Hdim + (part-2)*64;
    u16* dst = Ab + le*NPITCH + part*64;
    #pragma unroll
    for (int j=0;j<16;++j){
      const float4 v = ((const float4*)src)[j];
      ushort4 o; o.x=f2bf(v.x); o.y=f2bf(v.y); o.z=f2bf(v.z); o.w=f2bf(v.w);
      *(ushort4*)(dst + j*4) = o;
    }
  }
  __syncthreads();

  f32x4 acc[4][2];
  gemm_tile<8>(Ab, NPITCH, w_node1t, 256, node_b1, wv, cidx, hi, acc);
  __syncthreads();
  #pragma unroll
  for (int rt=0; rt<4; ++rt)
    #pragma unroll
    for (int j=0;j<2;++j){
      const int col = (wv*2+j)*16 + cidx;
      #pragma unroll
      for (int i=0;i<4;++i)
        Ab[(rt*16 + hi*4 + i)*NPITCH + col] = f2bf(silu_f(acc[rt][j][i]));
    }
  __syncthreads();
  gemm_tile<4>(Ab, NPITCH, w_node2t, 128, node_b2, wv, cidx, hi, acc);
  #pragma unroll
  for (int rt=0; rt<4; ++rt)
    #pragma unroll
    for (int j=0;j<2;++j){
      const int col = (wv*2+j)*16 + cidx;
      #pragma unroll
      for (int i=0;i<4;++i){
        const int row = rt*16 + hi*4 + i;
        const int g = r0 + row;
        if (g < N)
          out_h[(size_t)g*Hdim + col] = h[(size_t)g*Hdim + col] + acc[rt][j][i];
      }
    }
}

__global__ void egcl_init(float* __restrict__ agg, const float* __restrict__ coord,
                          float* __restrict__ out_coord, int nagg, int nc)
{
  const int i = blockIdx.x*256 + threadIdx.x;
  if (i < nagg) agg[i] = 0.f;
  if (i < nc)   out_coord[i] = coord[i];
}

// Wt[c][k] (bf16, zero-padded to Kpad) from W[k][c] (f32, [K,128])
__global__ void egcl_wconv(const float* __restrict__ src, u16* __restrict__ dst,
                           int K, int Kpad)
{
  const int i = blockIdx.x*256 + threadIdx.x;
  if (i >= 128*Kpad) return;
  const int c = i / Kpad, k = i - c*Kpad;
  const float v = (k < K) ? src[(size_t)k*128 + c] : 0.f;
  dst[i] = f2bf(v);
}

extern "C" void kernel_launch(void* const* d_in, const int* in_sizes, int n_in,
                              void* d_out, int out_size, void* d_ws, size_t ws_size,
                              hipStream_t stream)
{
  const float* h       = (const float*)d_in[0];
  const float* coord   = (const float*)d_in[1];
  const int*   ei      = (const int*)d_in[2];
  const float* ea      = (const float*)d_in[3];
  const float* mes_w1  = (const float*)d_in[4];
  const float* mes_b1  = (const float*)d_in[5];
  const float* mes_w2  = (const float*)d_in[6];
  const float* mes_b2  = (const float*)d_in[7];
  const float* edge_w1 = (const float*)d_in[8];
  const float* edge_b1 = (const float*)d_in[9];
  const float* edge_w2 = (const float*)d_in[10];
  const float* edge_b2 = (const float*)d_in[11];
  const float* node_w1 = (const float*)d_in[12];
  const float* node_b1 = (const float*)d_in[13];
  const float* node_w2 = (const float*)d_in[14];
  const float* node_b2 = (const float*)d_in[15];
  const float* coord_w1= (const float*)d_in[16];
  const float* coord_b1= (const float*)d_in[17];
  const float* coord_w2= (const float*)d_in[18];

  const int N = in_sizes[0] / Hdim;
  const int E = in_sizes[2] / 2;

  char* ws = (char*)d_ws;
  float* agg      = (float*)ws;                       // N*128 f32
  u16* w_mes1t    = (u16*)(ws + (size_t)N*Hdim*4);
  u16* w_mes2t    = w_mes1t  + 128*288;
  u16* w_coord1t  = w_mes2t  + 128*128;
  u16* w_edge1t   = w_coord1t+ 128*128;
  u16* w_edge2t   = w_edge1t + 128*160;
  u16* w_node1t   = w_edge2t + 128*128;
  u16* w_node2t   = w_node1t + 128*256;

  float* out_h     = (float*)d_out;
  float* out_coord = out_h + (size_t)N*Hdim;
  float* out_edge  = out_coord + (size_t)N*3;

  egcl_init<<<(N*Hdim + 255)/256, 256, 0, stream>>>(agg, coord, out_coord, N*Hdim, N*3);

  egcl_wconv<<<(128*288 + 255)/256, 256, 0, stream>>>(mes_w1,   w_mes1t,   273, 288);
  egcl_wconv<<<(128*128 + 255)/256, 256, 0, stream>>>(mes_w2,   w_mes2t,   128, 128);
  egcl_wconv<<<(128*128 + 255)/256, 256, 0, stream>>>(coord_w1, w_coord1t, 128, 128);
  egcl_wconv<<<(128*160 + 255)/256, 256, 0, stream>>>(edge_w1,  w_edge1t,  145, 160);
  egcl_wconv<<<(128*128 + 255)/256, 256, 0, stream>>>(edge_w2,  w_edge2t,  128, 128);
  egcl_wconv<<<(128*256 + 255)/256, 256, 0, stream>>>(node_w1,  w_node1t,  256, 256);
  egcl_wconv<<<(128*128 + 255)/256, 256, 0, stream>>>(node_w2,  w_node2t,  128, 128);

  egcl_edge<<<(E + 63)/64, 256, 0, stream>>>(h, coord, ei, ea,
      mes_b1, mes_b2, edge_b1, edge_b2, coord_b1, coord_w2,
      w_mes1t, w_mes2t, w_coord1t, w_edge1t, w_edge2t,
      agg, out_coord, out_edge, E, N);

  egcl_node<<<(N + 63)/64, 256, 0, stream>>>(h, agg, node_b1, node_b2,
      w_node1t, w_node2t, out_h, N);
}